// Round 1
// baseline (721.845 us; speedup 1.0000x reference)
//
#include <hip/hip_runtime.h>
#include <hip/hip_bf16.h>

#define Bb 2
#define Ss 2048
#define Hh 2048
#define NH 16
#define NKV 4
#define HD 128
#define NREP (NH / NKV)
#define Mrows (Bb * Ss)          // 4096
#define NQKV (NH*HD + 2*NKV*HD)  // 3072

using short8 = __attribute__((ext_vector_type(8))) short;
using f32x4  = __attribute__((ext_vector_type(4))) float;

__device__ __forceinline__ unsigned short f2b(float f) {
  union { float f; unsigned u; } v; v.f = f;
  return (unsigned short)((v.u + 0x7fffu + ((v.u >> 16) & 1u)) >> 16);
}
__device__ __forceinline__ float b2f(unsigned short h) {
  union { unsigned u; float f; } v; v.u = ((unsigned)h) << 16; return v.f;
}

__device__ __forceinline__ void gload16(const void* g, void* l) {
  __builtin_amdgcn_global_load_lds(
      (const __attribute__((address_space(1))) unsigned int*)g,
      (__attribute__((address_space(3))) unsigned int*)l, 16, 0, 0);
}

// ---------------- fp32 -> bf16 convert (row-major, same layout) ----------------
__global__ void cvt_bf16(const float* __restrict__ in, unsigned short* __restrict__ out, int n) {
  int i = (blockIdx.x * blockDim.x + threadIdx.x) * 4;
  if (i < n) {
    float4 f = *(const float4*)(in + i);
    ushort4 o;
    o.x = f2b(f.x); o.y = f2b(f.y); o.z = f2b(f.z); o.w = f2b(f.w);
    *(ushort4*)(out + i) = o;
  }
}

// ------------- transpose + convert: in (R x C fp32) -> out (C x R bf16) -------------
// out row stride = R. Launch grid (C/32, R/32), block (32,8).
__global__ void transpose_cvt(const float* __restrict__ in, unsigned short* __restrict__ out,
                              int R, int C) {
  __shared__ float tile[32][33];
  int c0 = blockIdx.x * 32, r0 = blockIdx.y * 32;
  int tx = threadIdx.x, ty = threadIdx.y;
  #pragma unroll
  for (int i = ty; i < 32; i += 8)
    tile[i][tx] = in[(long)(r0 + i) * C + c0 + tx];
  __syncthreads();
  #pragma unroll
  for (int i = ty; i < 32; i += 8)
    out[(long)(c0 + i) * R + r0 + tx] = f2b(tile[tx][i]);
}

// ---------------- bf16 GEMM: C(MxN) = A(MxK) * Bt(NxK)^T ----------------
// 128x128 tile, BK=32, 256 threads = 4 waves (2x2 of 64x64), global_load_lds staging.
template <bool OUT_BF16>
__global__ __launch_bounds__(256) void gemm_bt(const unsigned short* __restrict__ A,
                                               const unsigned short* __restrict__ Bt,
                                               void* __restrict__ Cv,
                                               int Mm, int Nn, int Kk) {
  __shared__ unsigned short As[128 * 32];
  __shared__ unsigned short Bs[128 * 32];
  const int t = threadIdx.x;
  const int lane = t & 63, wave = t >> 6;
  const int quad = lane >> 4, l16 = lane & 15;
  const int m0 = blockIdx.y * 128, n0 = blockIdx.x * 128;
  const int wm = (wave >> 1) * 64, wn = (wave & 1) * 64;

  f32x4 acc[4][4] = {};

  // staging source pointers (chunk c=0 -> rows 0..63, c=1 -> rows 64..127)
  const unsigned short* Ag0 = A + (long)(m0 + (t >> 2)) * Kk + (t & 3) * 8;
  const unsigned short* Ag1 = A + (long)(m0 + 64 + (t >> 2)) * Kk + (t & 3) * 8;
  const unsigned short* Bg0 = Bt + (long)(n0 + (t >> 2)) * Kk + (t & 3) * 8;
  const unsigned short* Bg1 = Bt + (long)(n0 + 64 + (t >> 2)) * Kk + (t & 3) * 8;
  unsigned short* lA0 = As + (wave * 64) * 8;
  unsigned short* lA1 = As + (wave * 64 + 256) * 8;
  unsigned short* lB0 = Bs + (wave * 64) * 8;
  unsigned short* lB1 = Bs + (wave * 64 + 256) * 8;

  for (int k0 = 0; k0 < Kk; k0 += 32) {
    gload16(Ag0 + k0, lA0);
    gload16(Ag1 + k0, lA1);
    gload16(Bg0 + k0, lB0);
    gload16(Bg1 + k0, lB1);
    __syncthreads();

    short8 af[4], bf[4];
    #pragma unroll
    for (int i = 0; i < 4; i++)
      af[i] = *(const short8*)(As + (wm + i * 16 + l16) * 32 + quad * 8);
    #pragma unroll
    for (int i = 0; i < 4; i++)
      bf[i] = *(const short8*)(Bs + (wn + i * 16 + l16) * 32 + quad * 8);

    #pragma unroll
    for (int mi = 0; mi < 4; mi++)
      #pragma unroll
      for (int ni = 0; ni < 4; ni++)
        acc[mi][ni] = __builtin_amdgcn_mfma_f32_16x16x32_bf16(af[mi], bf[ni], acc[mi][ni], 0, 0, 0);
    __syncthreads();
  }

  #pragma unroll
  for (int mi = 0; mi < 4; mi++)
    #pragma unroll
    for (int ni = 0; ni < 4; ni++)
      #pragma unroll
      for (int r = 0; r < 4; r++) {
        long row = m0 + wm + mi * 16 + quad * 4 + r;
        long col = n0 + wn + ni * 16 + l16;
        if (OUT_BF16)
          ((unsigned short*)Cv)[row * Nn + col] = f2b(acc[mi][ni][r]);
        else
          ((float*)Cv)[row * Nn + col] = acc[mi][ni][r];
      }
}

// ---------------- RoPE + reshape ----------------
// qkv: (Mrows, 3072) bf16 ->
//   qt (B,NH,S,HD) bf16 (roped), kt (B,NKV,S,HD) bf16 (roped), vt (B,NKV,HD,S) bf16
__global__ void rope_reshape(const unsigned short* __restrict__ qkv,
                             const float* __restrict__ cosT, const float* __restrict__ sinT,
                             unsigned short* __restrict__ qt, unsigned short* __restrict__ kt,
                             unsigned short* __restrict__ vt) {
  int row = blockIdx.x;                 // 0..4095
  int b = row / Ss, s = row % Ss;
  const unsigned short* r = qkv + (long)row * NQKV;
  for (int i = threadIdx.x; i < NQKV; i += blockDim.x) {
    if (i < NH * HD) {
      int h = i / HD, d = i % HD;
      float val = b2f(r[i]);
      float partner = b2f(r[h * HD + ((d < 64) ? d + 64 : d - 64)]);
      float c = cosT[s * HD + d], sn = sinT[s * HD + d];
      float o = val * c + ((d < 64) ? -partner : partner) * sn;
      qt[(((long)b * NH + h) * Ss + s) * HD + d] = f2b(o);
    } else if (i < NH * HD + NKV * HD) {
      int j = i - NH * HD;
      int h = j / HD, d = j % HD;
      float val = b2f(r[i]);
      float partner = b2f(r[NH * HD + h * HD + ((d < 64) ? d + 64 : d - 64)]);
      float c = cosT[s * HD + d], sn = sinT[s * HD + d];
      float o = val * c + ((d < 64) ? -partner : partner) * sn;
      kt[(((long)b * NKV + h) * Ss + s) * HD + d] = f2b(o);
    } else {
      int j = i - NH * HD - NKV * HD;
      int h = j / HD, d = j % HD;
      vt[(((long)b * NKV + h) * HD + d) * Ss + s] = r[i];
    }
  }
}

// ---------------- flash attention (causal, GQA) ----------------
// grid (S/64, NH, B), 256 threads = 4 waves; wave handles 16 q rows.
__global__ __launch_bounds__(256) void flash_attn(const unsigned short* __restrict__ qt,
                                                  const unsigned short* __restrict__ kt,
                                                  const unsigned short* __restrict__ vt,
                                                  unsigned short* __restrict__ out) {
  __shared__ unsigned short Pl[4][16 * 32];
  const int w = threadIdx.x >> 6, lane = threadIdx.x & 63;
  const int quad = lane >> 4, l16 = lane & 15;
  const int h = blockIdx.y, b = blockIdx.z;
  const int qblk = gridDim.x - 1 - blockIdx.x;   // big q first: better tail
  const int q0 = qblk * 64 + w * 16;
  const int kvh = h / NREP;

  const unsigned short* Qb = qt + ((long)b * NH + h) * Ss * HD;
  const unsigned short* Kb = kt + ((long)b * NKV + kvh) * Ss * HD;
  const unsigned short* Vb = vt + ((long)b * NKV + kvh) * HD * Ss;

  short8 aq[4];
  #pragma unroll
  for (int kc = 0; kc < 4; kc++)
    aq[kc] = *(const short8*)(Qb + (q0 + l16) * HD + kc * 32 + quad * 8);

  f32x4 accO[8] = {};
  float m_i[4], l_i[4];
  #pragma unroll
  for (int r = 0; r < 4; r++) { m_i[r] = -__builtin_inff(); l_i[r] = 0.f; }
  const float cscale = 1.4426950408889634f * 0.08838834764831845f; // log2e / sqrt(128)

  const int kend = q0 + 16;
  for (int k0 = 0; k0 < kend; k0 += 32) {
    // scores: S = Q K^T  (16 x 32)
    f32x4 sc[2] = {};
    #pragma unroll
    for (int nt = 0; nt < 2; nt++)
      #pragma unroll
      for (int kc = 0; kc < 4; kc++) {
        short8 bk = *(const short8*)(Kb + (k0 + nt * 16 + l16) * HD + kc * 32 + quad * 8);
        sc[nt] = __builtin_amdgcn_mfma_f32_16x16x32_bf16(aq[kc], bk, sc[nt], 0, 0, 0);
      }

    if (k0 + 31 > q0) {  // chunk touches the diagonal: mask
      #pragma unroll
      for (int nt = 0; nt < 2; nt++) {
        int kj = k0 + nt * 16 + l16;
        #pragma unroll
        for (int r = 0; r < 4; r++) {
          int qi = q0 + quad * 4 + r;
          if (kj > qi) sc[nt][r] = -__builtin_inff();
        }
      }
    }

    // online softmax (rows live within 16-lane quads)
    float mx[4];
    #pragma unroll
    for (int r = 0; r < 4; r++) {
      float v = fmaxf(sc[0][r], sc[1][r]);
      v = fmaxf(v, __shfl_xor(v, 1));
      v = fmaxf(v, __shfl_xor(v, 2));
      v = fmaxf(v, __shfl_xor(v, 4));
      v = fmaxf(v, __shfl_xor(v, 8));
      mx[r] = v;
    }
    #pragma unroll
    for (int r = 0; r < 4; r++) {
      float mn = fmaxf(m_i[r], mx[r]);
      float alpha = exp2f((m_i[r] - mn) * cscale);
      m_i[r] = mn;
      l_i[r] *= alpha;
      #pragma unroll
      for (int nt = 0; nt < 8; nt++) accO[nt][r] *= alpha;
    }

    unsigned short* P = Pl[w];
    float rsum[4] = {0.f, 0.f, 0.f, 0.f};
    #pragma unroll
    for (int nt = 0; nt < 2; nt++)
      #pragma unroll
      for (int r = 0; r < 4; r++) {
        float p = exp2f((sc[nt][r] - m_i[r]) * cscale);
        rsum[r] += p;
        P[(quad * 4 + r) * 32 + nt * 16 + l16] = f2b(p);
      }
    #pragma unroll
    for (int r = 0; r < 4; r++) {
      float v = rsum[r];
      v += __shfl_xor(v, 1);
      v += __shfl_xor(v, 2);
      v += __shfl_xor(v, 4);
      v += __shfl_xor(v, 8);
      l_i[r] += v;
    }

    asm volatile("s_waitcnt lgkmcnt(0)" ::: "memory");

    // PV: A = P (16x32, A-layout from LDS), B = V^T chunk
    short8 ap = *(const short8*)(P + l16 * 32 + quad * 8);
    #pragma unroll
    for (int nt = 0; nt < 8; nt++) {
      short8 bv = *(const short8*)(Vb + (long)(nt * 16 + l16) * Ss + k0 + quad * 8);
      accO[nt] = __builtin_amdgcn_mfma_f32_16x16x32_bf16(ap, bv, accO[nt], 0, 0, 0);
    }
  }

  // epilogue: out[b][s][h*HD+d] bf16
  #pragma unroll
  for (int r = 0; r < 4; r++) {
    float inv = 1.f / l_i[r];
    long orow = (long)b * Ss + q0 + quad * 4 + r;
    #pragma unroll
    for (int nt = 0; nt < 8; nt++)
      out[orow * (NH * HD) + h * HD + nt * 16 + l16] = f2b(accO[nt][r] * inv);
  }
}

extern "C" void kernel_launch(void* const* d_in, const int* in_sizes, int n_in,
                              void* d_out, int out_size, void* d_ws, size_t ws_size,
                              hipStream_t stream) {
  const float* x   = (const float*)d_in[0];
  const float* cosT = (const float*)d_in[1];
  const float* sinT = (const float*)d_in[2];
  const float* wq  = (const float*)d_in[3];
  const float* wk  = (const float*)d_in[4];
  const float* wv  = (const float*)d_in[5];
  const float* wo  = (const float*)d_in[6];
  float* out = (float*)d_out;

  char* ws = (char*)d_ws;
  // workspace layout (bytes)
  unsigned short* xb    = (unsigned short*)(ws + 0);             // 4096x2048 bf16 = 16 MiB
  unsigned short* wqkvt = (unsigned short*)(ws + 16777216);      // 3072x2048 bf16 = 12 MiB
  unsigned short* wot   = (unsigned short*)(ws + 29360128);      // 2048x2048 bf16 = 8 MiB
  unsigned short* qkv   = (unsigned short*)(ws + 37748736);      // 4096x3072 bf16 = 24 MiB
  unsigned short* kt    = (unsigned short*)(ws + 62914560);      // 4 MiB
  unsigned short* vt    = (unsigned short*)(ws + 67108864);      // 4 MiB
  unsigned short* qt    = xb;    // alias: xb dead after GEMM1
  unsigned short* attno = qkv;   // alias: qkv dead after rope

  // 1. x -> bf16
  cvt_bf16<<<Mrows * Hh / 4 / 256, 256, 0, stream>>>(x, xb, Mrows * Hh);

  // 2. weight transposes (K x N fp32 -> N x K bf16)
  dim3 tb(32, 8);
  transpose_cvt<<<dim3(Hh / 32, Hh / 32), tb, 0, stream>>>(wq, wqkvt, Hh, NH * HD);
  transpose_cvt<<<dim3(NKV * HD / 32, Hh / 32), tb, 0, stream>>>(wk, wqkvt + (long)NH * HD * Hh, Hh, NKV * HD);
  transpose_cvt<<<dim3(NKV * HD / 32, Hh / 32), tb, 0, stream>>>(wv, wqkvt + (long)(NH * HD + NKV * HD) * Hh, Hh, NKV * HD);
  transpose_cvt<<<dim3(Hh / 32, Hh / 32), tb, 0, stream>>>(wo, wot, Hh, Hh);

  // 3. QKV = x @ Wqkv  (4096 x 3072 x 2048), bf16 out
  gemm_bt<true><<<dim3(NQKV / 128, Mrows / 128), 256, 0, stream>>>(xb, wqkvt, qkv, Mrows, NQKV, Hh);

  // 4. RoPE + reshape
  rope_reshape<<<Mrows, 256, 0, stream>>>(qkv, cosT, sinT, qt, kt, vt);

  // 5. flash attention
  flash_attn<<<dim3(Ss / 64, NH, Bb), 256, 0, stream>>>(qt, kt, vt, attno);

  // 6. out = attno @ wo  (4096 x 2048 x 2048), fp32 out
  gemm_bt<false><<<dim3(Hh / 128, Mrows / 128), 256, 0, stream>>>(attno, wot, out, Mrows, Hh, Hh);
}

// Round 2
// 365.312 us; speedup vs baseline: 1.9760x; 1.9760x over previous
//
#include <hip/hip_runtime.h>
#include <hip/hip_bf16.h>

#define Bb 2
#define Ss 2048
#define Hh 2048
#define NH 16
#define NKV 4
#define HD 128
#define NREP (NH / NKV)
#define Mrows (Bb * Ss)          // 4096
#define NQKV (NH*HD + 2*NKV*HD)  // 3072

using short8 = __attribute__((ext_vector_type(8))) short;
using f32x4  = __attribute__((ext_vector_type(4))) float;

__device__ __forceinline__ unsigned short f2b(float f) {
  union { float f; unsigned u; } v; v.f = f;
  return (unsigned short)((v.u + 0x7fffu + ((v.u >> 16) & 1u)) >> 16);
}
__device__ __forceinline__ float b2f(unsigned short h) {
  union { unsigned u; float f; } v; v.u = ((unsigned)h) << 16; return v.f;
}

__device__ __forceinline__ void gload16(const void* g, void* l) {
  __builtin_amdgcn_global_load_lds(
      (const __attribute__((address_space(1))) unsigned int*)g,
      (__attribute__((address_space(3))) unsigned int*)l, 16, 0, 0);
}

// ---------------- fp32 -> bf16 convert (row-major, same layout) ----------------
__global__ void cvt_bf16(const float* __restrict__ in, unsigned short* __restrict__ out, int n) {
  int i = (blockIdx.x * blockDim.x + threadIdx.x) * 4;
  if (i < n) {
    float4 f = *(const float4*)(in + i);
    ushort4 o;
    o.x = f2b(f.x); o.y = f2b(f.y); o.z = f2b(f.z); o.w = f2b(f.w);
    *(ushort4*)(out + i) = o;
  }
}

// ------------- transpose + convert: in (R x C fp32) -> out (C x R bf16) -------------
__global__ void transpose_cvt(const float* __restrict__ in, unsigned short* __restrict__ out,
                              int R, int C) {
  __shared__ float tile[32][33];
  int c0 = blockIdx.x * 32, r0 = blockIdx.y * 32;
  int tx = threadIdx.x, ty = threadIdx.y;
  #pragma unroll
  for (int i = ty; i < 32; i += 8)
    tile[i][tx] = in[(long)(r0 + i) * C + c0 + tx];
  __syncthreads();
  #pragma unroll
  for (int i = ty; i < 32; i += 8)
    out[(long)(c0 + i) * R + r0 + tx] = f2b(tile[tx][i]);
}

// ---------------- bf16 GEMM: C(MxN) = A(MxK) * Bt(NxK)^T ----------------
template <bool OUT_BF16>
__global__ __launch_bounds__(256) void gemm_bt(const unsigned short* __restrict__ A,
                                               const unsigned short* __restrict__ Bt,
                                               void* __restrict__ Cv,
                                               int Mm, int Nn, int Kk) {
  __shared__ unsigned short As[128 * 32];
  __shared__ unsigned short Bs[128 * 32];
  const int t = threadIdx.x;
  const int lane = t & 63, wave = t >> 6;
  const int quad = lane >> 4, l16 = lane & 15;
  const int m0 = blockIdx.y * 128, n0 = blockIdx.x * 128;
  const int wm = (wave >> 1) * 64, wn = (wave & 1) * 64;

  f32x4 acc[4][4] = {};

  const unsigned short* Ag0 = A + (long)(m0 + (t >> 2)) * Kk + (t & 3) * 8;
  const unsigned short* Ag1 = A + (long)(m0 + 64 + (t >> 2)) * Kk + (t & 3) * 8;
  const unsigned short* Bg0 = Bt + (long)(n0 + (t >> 2)) * Kk + (t & 3) * 8;
  const unsigned short* Bg1 = Bt + (long)(n0 + 64 + (t >> 2)) * Kk + (t & 3) * 8;
  unsigned short* lA0 = As + (wave * 64) * 8;
  unsigned short* lA1 = As + (wave * 64 + 256) * 8;
  unsigned short* lB0 = Bs + (wave * 64) * 8;
  unsigned short* lB1 = Bs + (wave * 64 + 256) * 8;

  for (int k0 = 0; k0 < Kk; k0 += 32) {
    gload16(Ag0 + k0, lA0);
    gload16(Ag1 + k0, lA1);
    gload16(Bg0 + k0, lB0);
    gload16(Bg1 + k0, lB1);
    __syncthreads();

    short8 af[4], bf[4];
    #pragma unroll
    for (int i = 0; i < 4; i++)
      af[i] = *(const short8*)(As + (wm + i * 16 + l16) * 32 + quad * 8);
    #pragma unroll
    for (int i = 0; i < 4; i++)
      bf[i] = *(const short8*)(Bs + (wn + i * 16 + l16) * 32 + quad * 8);

    #pragma unroll
    for (int mi = 0; mi < 4; mi++)
      #pragma unroll
      for (int ni = 0; ni < 4; ni++)
        acc[mi][ni] = __builtin_amdgcn_mfma_f32_16x16x32_bf16(af[mi], bf[ni], acc[mi][ni], 0, 0, 0);
    __syncthreads();
  }

  #pragma unroll
  for (int mi = 0; mi < 4; mi++)
    #pragma unroll
    for (int ni = 0; ni < 4; ni++)
      #pragma unroll
      for (int r = 0; r < 4; r++) {
        long row = m0 + wm + mi * 16 + quad * 4 + r;
        long col = n0 + wn + ni * 16 + l16;
        if (OUT_BF16)
          ((unsigned short*)Cv)[row * Nn + col] = f2b(acc[mi][ni][r]);
        else
          ((float*)Cv)[row * Nn + col] = acc[mi][ni][r];
      }
}

// ---------------- RoPE + reshape ----------------
__global__ void rope_reshape(const unsigned short* __restrict__ qkv,
                             const float* __restrict__ cosT, const float* __restrict__ sinT,
                             unsigned short* __restrict__ qt, unsigned short* __restrict__ kt,
                             unsigned short* __restrict__ vt) {
  int row = blockIdx.x;                 // 0..4095
  int b = row / Ss, s = row % Ss;
  const unsigned short* r = qkv + (long)row * NQKV;
  for (int i = threadIdx.x; i < NQKV; i += blockDim.x) {
    if (i < NH * HD) {
      int h = i / HD, d = i % HD;
      float val = b2f(r[i]);
      float partner = b2f(r[h * HD + ((d < 64) ? d + 64 : d - 64)]);
      float c = cosT[s * HD + d], sn = sinT[s * HD + d];
      float o = val * c + ((d < 64) ? -partner : partner) * sn;
      qt[(((long)b * NH + h) * Ss + s) * HD + d] = f2b(o);
    } else if (i < NH * HD + NKV * HD) {
      int j = i - NH * HD;
      int h = j / HD, d = j % HD;
      float val = b2f(r[i]);
      float partner = b2f(r[NH * HD + h * HD + ((d < 64) ? d + 64 : d - 64)]);
      float c = cosT[s * HD + d], sn = sinT[s * HD + d];
      float o = val * c + ((d < 64) ? -partner : partner) * sn;
      kt[(((long)b * NKV + h) * Ss + s) * HD + d] = f2b(o);
    } else {
      int j = i - NH * HD - NKV * HD;
      int h = j / HD, d = j % HD;
      vt[(((long)b * NKV + h) * HD + d) * Ss + s] = r[i];
    }
  }
}

// ---------------- flash attention v2: LDS-staged, double-buffered, swizzled ----------------
// 1D grid of (S/64)*NH*B = 1024 blocks, 4 waves; wave owns 16 q rows; 64-key chunks.
// LDS: K[2][64x128] swizzled (granule c at row r holds col-granule c^(r&15)),
//      V[2][128x64] swizzled (granule c at row r holds key-granule c^(r&7)),
//      P[4][16x72] (+8 shorts row pad).
__global__ __launch_bounds__(256, 2) void flash_attn(const unsigned short* __restrict__ qt,
                                                     const unsigned short* __restrict__ kt,
                                                     const unsigned short* __restrict__ vt,
                                                     unsigned short* __restrict__ out) {
  __shared__ unsigned short Ks[2][64 * 128];
  __shared__ unsigned short Vs[2][128 * 64];
  __shared__ unsigned short Ps[4][16 * 72];

  const int w = threadIdx.x >> 6, lane = threadIdx.x & 63;
  const int quad = lane >> 4, l16 = lane & 15;
  const int idx = blockIdx.x;
  const int qblk = (Ss / 64) - 1 - (idx >> 5);   // longest blocks dispatched first
  const int bh = idx & 31;
  const int h = bh & (NH - 1), b = bh >> 4;
  const int q0 = qblk * 64 + w * 16;
  const int kvh = h / NREP;

  const unsigned short* Qb = qt + ((long)b * NH + h) * Ss * HD;
  const unsigned short* Kb = kt + ((long)b * NKV + kvh) * Ss * HD;
  const unsigned short* Vb = vt + ((long)b * NKV + kvh) * HD * Ss;
  unsigned short* Pw = Ps[w];

  const int nch = qblk + 1;
  const int r8 = lane >> 3, c8 = lane & 7;

  // stage chunk 0 into buffer 0
  {
    #pragma unroll
    for (int i = 0; i < 4; i++) {
      int r = i * 16 + w * 4 + quad;
      int sg = l16 ^ (w * 4 + quad);
      gload16(Kb + (long)r * HD + sg * 8, &Ks[0][(i * 256 + w * 64) * 8]);
    }
    #pragma unroll
    for (int i = 0; i < 4; i++) {
      int r = i * 32 + w * 8 + r8;
      int sg = c8 ^ r8;
      gload16(Vb + (long)r * Ss + sg * 8, &Vs[0][(i * 256 + w * 64) * 8]);
    }
  }

  short8 aq[4];
  #pragma unroll
  for (int kc = 0; kc < 4; kc++)
    aq[kc] = *(const short8*)(Qb + (long)(q0 + l16) * HD + kc * 32 + quad * 8);

  f32x4 accO[8] = {};
  float m_i[4], l_i[4];
  #pragma unroll
  for (int r = 0; r < 4; r++) { m_i[r] = -__builtin_inff(); l_i[r] = 0.f; }
  const float cscale = 1.4426950408889634f * 0.08838834764831845f; // log2e / sqrt(128)

  for (int c = 0; c < nch; ++c) {
    const unsigned short* Ksb = Ks[c & 1];
    const unsigned short* Vsb = Vs[c & 1];

    if (c + 1 < nch) {
      const int k0 = (c + 1) * 64;
      unsigned short* Kd = Ks[(c + 1) & 1];
      unsigned short* Vd = Vs[(c + 1) & 1];
      #pragma unroll
      for (int i = 0; i < 4; i++) {
        int r = i * 16 + w * 4 + quad;
        int sg = l16 ^ (w * 4 + quad);
        gload16(Kb + (long)(k0 + r) * HD + sg * 8, Kd + (i * 256 + w * 64) * 8);
      }
      #pragma unroll
      for (int i = 0; i < 4; i++) {
        int r = i * 32 + w * 8 + r8;
        int sg = c8 ^ r8;
        gload16(Vb + (long)r * Ss + k0 + sg * 8, Vd + (i * 256 + w * 64) * 8);
      }
      asm volatile("s_waitcnt vmcnt(8)" ::: "memory");   // drain current buf; keep next in flight
    } else {
      asm volatile("s_waitcnt vmcnt(0)" ::: "memory");
    }
    asm volatile("s_barrier" ::: "memory");

    // scores: 16 x 64
    f32x4 sc[4] = {};
    #pragma unroll
    for (int kc = 0; kc < 4; kc++)
      #pragma unroll
      for (int nt = 0; nt < 4; nt++) {
        short8 bk = *(const short8*)(Ksb + ((nt * 16 + l16) * 16 + ((kc * 4 + quad) ^ l16)) * 8);
        sc[nt] = __builtin_amdgcn_mfma_f32_16x16x32_bf16(aq[kc], bk, sc[nt], 0, 0, 0);
      }

    if (c == nch - 1) {  // diagonal chunk: causal mask
      #pragma unroll
      for (int nt = 0; nt < 4; nt++) {
        int kj = c * 64 + nt * 16 + l16;
        #pragma unroll
        for (int r = 0; r < 4; r++)
          if (kj > q0 + quad * 4 + r) sc[nt][r] = -__builtin_inff();
      }
    }

    // online softmax
    float mx[4];
    #pragma unroll
    for (int r = 0; r < 4; r++) {
      float v = fmaxf(fmaxf(sc[0][r], sc[1][r]), fmaxf(sc[2][r], sc[3][r]));
      v = fmaxf(v, __shfl_xor(v, 1));
      v = fmaxf(v, __shfl_xor(v, 2));
      v = fmaxf(v, __shfl_xor(v, 4));
      v = fmaxf(v, __shfl_xor(v, 8));
      mx[r] = v;
    }
    float rsum[4];
    #pragma unroll
    for (int r = 0; r < 4; r++) {
      float mn = fmaxf(m_i[r], mx[r]);
      float alpha = __builtin_amdgcn_exp2f((m_i[r] - mn) * cscale);
      m_i[r] = mn;
      l_i[r] *= alpha;
      #pragma unroll
      for (int nt = 0; nt < 8; nt++) accO[nt][r] *= alpha;
      rsum[r] = 0.f;
      #pragma unroll
      for (int nt = 0; nt < 4; nt++) {
        float p = __builtin_amdgcn_exp2f((sc[nt][r] - mn) * cscale);
        rsum[r] += p;
        Pw[(quad * 4 + r) * 72 + nt * 16 + l16] = f2b(p);
      }
    }
    #pragma unroll
    for (int r = 0; r < 4; r++) {
      float v = rsum[r];
      v += __shfl_xor(v, 1);
      v += __shfl_xor(v, 2);
      v += __shfl_xor(v, 4);
      v += __shfl_xor(v, 8);
      l_i[r] += v;
    }

    // PV: A = P (16x64), B = V^T chunk from LDS
    short8 ap0 = *(const short8*)(Pw + l16 * 72 + quad * 8);
    short8 ap1 = *(const short8*)(Pw + l16 * 72 + 32 + quad * 8);
    #pragma unroll
    for (int nt = 0; nt < 8; nt++) {
      short8 bv0 = *(const short8*)(Vsb + ((nt * 16 + l16) * 8 + (quad ^ c8 ^ (r8 & 1) * 0 ^ (l16 & 7) ^ c8 ^ (l16 & 7) * 0)) * 8);
      // (kept simple below; the expression above is replaced)
      (void)bv0;
      break;
    }
    #pragma unroll
    for (int nt = 0; nt < 8; nt++) {
      short8 bv0 = *(const short8*)(Vsb + ((nt * 16 + l16) * 8 + (quad ^ (l16 & 7))) * 8);
      short8 bv1 = *(const short8*)(Vsb + ((nt * 16 + l16) * 8 + ((4 + quad) ^ (l16 & 7))) * 8);
      accO[nt] = __builtin_amdgcn_mfma_f32_16x16x32_bf16(ap0, bv0, accO[nt], 0, 0, 0);
      accO[nt] = __builtin_amdgcn_mfma_f32_16x16x32_bf16(ap1, bv1, accO[nt], 0, 0, 0);
    }

    asm volatile("s_waitcnt lgkmcnt(0)" ::: "memory");
    asm volatile("s_barrier" ::: "memory");
  }

  // epilogue
  #pragma unroll
  for (int r = 0; r < 4; r++) {
    float inv = 1.f / l_i[r];
    long orow = (long)b * Ss + q0 + quad * 4 + r;
    #pragma unroll
    for (int nt = 0; nt < 8; nt++)
      out[orow * (NH * HD) + h * HD + nt * 16 + l16] = f2b(accO[nt][r] * inv);
  }
}

extern "C" void kernel_launch(void* const* d_in, const int* in_sizes, int n_in,
                              void* d_out, int out_size, void* d_ws, size_t ws_size,
                              hipStream_t stream) {
  const float* x   = (const float*)d_in[0];
  const float* cosT = (const float*)d_in[1];
  const float* sinT = (const float*)d_in[2];
  const float* wq  = (const float*)d_in[3];
  const float* wk  = (const float*)d_in[4];
  const float* wv  = (const float*)d_in[5];
  const float* wo  = (const float*)d_in[6];
  float* out = (float*)d_out;

  char* ws = (char*)d_ws;
  unsigned short* xb    = (unsigned short*)(ws + 0);             // 16 MiB
  unsigned short* wqkvt = (unsigned short*)(ws + 16777216);      // 12 MiB
  unsigned short* wot   = (unsigned short*)(ws + 29360128);      // 8 MiB
  unsigned short* qkv   = (unsigned short*)(ws + 37748736);      // 24 MiB
  unsigned short* kt    = (unsigned short*)(ws + 62914560);      // 4 MiB
  unsigned short* vt    = (unsigned short*)(ws + 67108864);      // 4 MiB
  unsigned short* qt    = xb;    // alias: xb dead after GEMM1
  unsigned short* attno = qkv;   // alias: qkv dead after rope

  cvt_bf16<<<Mrows * Hh / 4 / 256, 256, 0, stream>>>(x, xb, Mrows * Hh);

  dim3 tb(32, 8);
  transpose_cvt<<<dim3(Hh / 32, Hh / 32), tb, 0, stream>>>(wq, wqkvt, Hh, NH * HD);
  transpose_cvt<<<dim3(NKV * HD / 32, Hh / 32), tb, 0, stream>>>(wk, wqkvt + (long)NH * HD * Hh, Hh, NKV * HD);
  transpose_cvt<<<dim3(NKV * HD / 32, Hh / 32), tb, 0, stream>>>(wv, wqkvt + (long)(NH * HD + NKV * HD) * Hh, Hh, NKV * HD);
  transpose_cvt<<<dim3(Hh / 32, Hh / 32), tb, 0, stream>>>(wo, wot, Hh, Hh);

  gemm_bt<true><<<dim3(NQKV / 128, Mrows / 128), 256, 0, stream>>>(xb, wqkvt, qkv, Mrows, NQKV, Hh);

  rope_reshape<<<Mrows, 256, 0, stream>>>(qkv, cosT, sinT, qt, kt, vt);

  flash_attn<<<(Ss / 64) * NH * Bb, 256, 0, stream>>>(qt, kt, vt, attno);

  gemm_bt<false><<<dim3(Hh / 128, Mrows / 128), 256, 0, stream>>>(attno, wot, out, Mrows, Hh, Hh);
}

// Round 3
// 343.359 us; speedup vs baseline: 2.1023x; 1.0639x over previous
//
#include <hip/hip_runtime.h>
#include <hip/hip_bf16.h>

#define Bb 2
#define Ss 2048
#define Hh 2048
#define NH 16
#define NKV 4
#define HD 128
#define NREP (NH / NKV)
#define Mrows (Bb * Ss)          // 4096
#define NQKV (NH*HD + 2*NKV*HD)  // 3072

using short8 = __attribute__((ext_vector_type(8))) short;
using f32x4  = __attribute__((ext_vector_type(4))) float;

__device__ __forceinline__ unsigned short f2b(float f) {
  union { float f; unsigned u; } v; v.f = f;
  return (unsigned short)((v.u + 0x7fffu + ((v.u >> 16) & 1u)) >> 16);
}
__device__ __forceinline__ float b2f(unsigned short h) {
  union { unsigned u; float f; } v; v.u = ((unsigned)h) << 16; return v.f;
}

__device__ __forceinline__ void gload16(const void* g, void* l) {
  __builtin_amdgcn_global_load_lds(
      (const __attribute__((address_space(1))) unsigned int*)g,
      (__attribute__((address_space(3))) unsigned int*)l, 16, 0, 0);
}

// ---------------- fp32 -> bf16 convert ----------------
__global__ void cvt_bf16(const float* __restrict__ in, unsigned short* __restrict__ out, int n) {
  int i = (blockIdx.x * blockDim.x + threadIdx.x) * 4;
  if (i < n) {
    float4 f = *(const float4*)(in + i);
    ushort4 o;
    o.x = f2b(f.x); o.y = f2b(f.y); o.z = f2b(f.z); o.w = f2b(f.w);
    *(ushort4*)(out + i) = o;
  }
}

// ------------- transpose + convert: in (R x C fp32) -> out (C x R bf16) -------------
__global__ void transpose_cvt(const float* __restrict__ in, unsigned short* __restrict__ out,
                              int R, int C) {
  __shared__ float tile[32][33];
  int c0 = blockIdx.x * 32, r0 = blockIdx.y * 32;
  int tx = threadIdx.x, ty = threadIdx.y;
  #pragma unroll
  for (int i = ty; i < 32; i += 8)
    tile[i][tx] = in[(long)(r0 + i) * C + c0 + tx];
  __syncthreads();
  #pragma unroll
  for (int i = ty; i < 32; i += 8)
    out[(long)(c0 + i) * R + r0 + tx] = f2b(tile[tx][i]);
}

// ---------------- bf16 GEMM: C(MxN) = A(MxK) * Bt(NxK)^T ----------------
template <bool OUT_BF16>
__global__ __launch_bounds__(256) void gemm_bt(const unsigned short* __restrict__ A,
                                               const unsigned short* __restrict__ Bt,
                                               void* __restrict__ Cv,
                                               int Mm, int Nn, int Kk) {
  __shared__ unsigned short As[128 * 32];
  __shared__ unsigned short Bs[128 * 32];
  const int t = threadIdx.x;
  const int lane = t & 63, wave = t >> 6;
  const int quad = lane >> 4, l16 = lane & 15;
  const int m0 = blockIdx.y * 128, n0 = blockIdx.x * 128;
  const int wm = (wave >> 1) * 64, wn = (wave & 1) * 64;

  f32x4 acc[4][4] = {};

  const unsigned short* Ag0 = A + (long)(m0 + (t >> 2)) * Kk + (t & 3) * 8;
  const unsigned short* Ag1 = A + (long)(m0 + 64 + (t >> 2)) * Kk + (t & 3) * 8;
  const unsigned short* Bg0 = Bt + (long)(n0 + (t >> 2)) * Kk + (t & 3) * 8;
  const unsigned short* Bg1 = Bt + (long)(n0 + 64 + (t >> 2)) * Kk + (t & 3) * 8;
  unsigned short* lA0 = As + (wave * 64) * 8;
  unsigned short* lA1 = As + (wave * 64 + 256) * 8;
  unsigned short* lB0 = Bs + (wave * 64) * 8;
  unsigned short* lB1 = Bs + (wave * 64 + 256) * 8;

  for (int k0 = 0; k0 < Kk; k0 += 32) {
    gload16(Ag0 + k0, lA0);
    gload16(Ag1 + k0, lA1);
    gload16(Bg0 + k0, lB0);
    gload16(Bg1 + k0, lB1);
    __syncthreads();

    short8 af[4], bf[4];
    #pragma unroll
    for (int i = 0; i < 4; i++)
      af[i] = *(const short8*)(As + (wm + i * 16 + l16) * 32 + quad * 8);
    #pragma unroll
    for (int i = 0; i < 4; i++)
      bf[i] = *(const short8*)(Bs + (wn + i * 16 + l16) * 32 + quad * 8);

    #pragma unroll
    for (int mi = 0; mi < 4; mi++)
      #pragma unroll
      for (int ni = 0; ni < 4; ni++)
        acc[mi][ni] = __builtin_amdgcn_mfma_f32_16x16x32_bf16(af[mi], bf[ni], acc[mi][ni], 0, 0, 0);
    __syncthreads();
  }

  #pragma unroll
  for (int mi = 0; mi < 4; mi++)
    #pragma unroll
    for (int ni = 0; ni < 4; ni++)
      #pragma unroll
      for (int r = 0; r < 4; r++) {
        long row = m0 + wm + mi * 16 + quad * 4 + r;
        long col = n0 + wn + ni * 16 + l16;
        if (OUT_BF16)
          ((unsigned short*)Cv)[row * Nn + col] = f2b(acc[mi][ni][r]);
        else
          ((float*)Cv)[row * Nn + col] = acc[mi][ni][r];
      }
}

// ---------------- RoPE for q,k (coalesced; uses cos[d+64]==cos[d]) ----------------
__global__ void rope_qk(const unsigned short* __restrict__ qkv,
                        const float* __restrict__ cosT, const float* __restrict__ sinT,
                        unsigned short* __restrict__ qt, unsigned short* __restrict__ kt) {
  int row = blockIdx.x;                 // 0..4095
  int b = row >> 11, s = row & (Ss - 1);
  const unsigned short* r = qkv + (long)row * NQKV;
  for (int jj = threadIdx.x; jj < (NH + NKV) * 64; jj += 256) {
    int hh = jj >> 6, d = jj & 63;
    float c = cosT[s * HD + d], sn = sinT[s * HD + d];
    float x0 = b2f(r[hh * 128 + d]), x1 = b2f(r[hh * 128 + 64 + d]);
    float o0 = x0 * c - x1 * sn;
    float o1 = x1 * c + x0 * sn;
    if (hh < NH) {
      unsigned short* dst = qt + (((long)b * NH + hh) * Ss + s) * HD + d;
      dst[0] = f2b(o0); dst[64] = f2b(o1);
    } else {
      unsigned short* dst = kt + (((long)b * NKV + (hh - NH)) * Ss + s) * HD + d;
      dst[0] = f2b(o0); dst[64] = f2b(o1);
    }
  }
}

// ---------------- V transpose: qkv v-part (s major) -> vt (B,NKV,HD,S) ----------------
__global__ void vtrans(const unsigned short* __restrict__ qkv, unsigned short* __restrict__ vt) {
  __shared__ unsigned short tile[32][33];
  int bh = blockIdx.z;                       // b*NKV + kvh
  int b = bh >> 2, kvh = bh & 3;
  int d0 = blockIdx.y * 32, s0 = blockIdx.x * 32;
  int tx = threadIdx.x, ty = threadIdx.y;
  #pragma unroll
  for (int i = ty; i < 32; i += 8)
    tile[i][tx] = qkv[(long)(b * Ss + s0 + i) * NQKV + (NH + NKV) * HD + kvh * HD + d0 + tx];
  __syncthreads();
  #pragma unroll
  for (int i = ty; i < 32; i += 8)
    vt[((long)bh * HD + d0 + i) * Ss + s0 + tx] = tile[tx][i];
}

// ---------------- flash attention v3: S^T form, in-register P, 2 q-tiles/wave ----------------
// grid = 512 blocks (16 qblks x 32 bh), 4 waves; wave owns 32 q rows (2 tiles); 64-key chunks.
// K LDS rows are key-permuted within 32-groups so S^T C-layout regs ARE the PV B-fragment.
__global__ __launch_bounds__(256, 2) void flash_attn(const unsigned short* __restrict__ qt,
                                                     const unsigned short* __restrict__ kt,
                                                     const unsigned short* __restrict__ vt,
                                                     unsigned short* __restrict__ out) {
  __shared__ unsigned short Ks[2][64 * 128];
  __shared__ unsigned short Vs[2][128 * 64];

  const int w = threadIdx.x >> 6, lane = threadIdx.x & 63;
  const int quad = lane >> 4, l16 = lane & 15;
  const int r8 = lane >> 3, c8 = lane & 7;
  const int idx = blockIdx.x;
  const int t5 = idx >> 5;
  const int qblk = (idx < 256) ? (15 - t5) : (t5 - 8);  // pair big+small qblk per CU
  const int bh = idx & 31;
  const int h = bh & (NH - 1), b = bh >> 4;
  const int q0w = qblk * 128 + w * 32;
  const int kvh = h / NREP;

  const unsigned short* Qb = qt + ((long)b * NH + h) * Ss * HD;
  const unsigned short* Kb = kt + ((long)b * NKV + kvh) * Ss * HD;
  const unsigned short* Vb = vt + ((long)b * NKV + kvh) * HD * Ss;
  const int nch = (qblk + 1) * 2;

  // ---- stage chunk 0 into buffer 0 ----
  #pragma unroll
  for (int i = 0; i < 4; i++) {
    int rho = i * 16 + w * 4 + quad;
    int key = (rho & 32) + ((rho >> 2) & 3) * 8 + ((rho >> 4) & 1) * 4 + (rho & 3);
    int sg = l16 ^ (w * 4 + quad);
    gload16(Kb + (long)key * HD + sg * 8, &Ks[0][(i * 256 + w * 64) * 8]);
  }
  #pragma unroll
  for (int i = 0; i < 4; i++) {
    int dv = i * 32 + w * 8 + r8;
    int sg = c8 ^ r8;
    gload16(Vb + (long)dv * Ss + sg * 8, &Vs[0][(i * 256 + w * 64) * 8]);
  }

  // ---- Q fragments (B-operand layout), 2 q-tiles ----
  short8 qf[2][4];
  #pragma unroll
  for (int qi = 0; qi < 2; qi++)
    #pragma unroll
    for (int kc = 0; kc < 4; kc++)
      qf[qi][kc] = *(const short8*)(Qb + (long)(q0w + qi * 16 + l16) * HD + kc * 32 + quad * 8);

  f32x4 accO[2][8] = {};
  float m_i[2], l_i[2];
  m_i[0] = m_i[1] = -__builtin_inff();
  l_i[0] = l_i[1] = 0.f;
  const float cscale = 1.4426950408889634f * 0.08838834764831845f; // log2e / sqrt(128)

  for (int c = 0; c < nch; ++c) {
    const unsigned short* Ksb = Ks[c & 1];
    const unsigned short* Vsb = Vs[c & 1];

    if (c + 1 < nch) {
      const int k0 = (c + 1) * 64;
      unsigned short* Kd = Ks[(c + 1) & 1];
      unsigned short* Vd = Vs[(c + 1) & 1];
      #pragma unroll
      for (int i = 0; i < 4; i++) {
        int rho = i * 16 + w * 4 + quad;
        int key = (rho & 32) + ((rho >> 2) & 3) * 8 + ((rho >> 4) & 1) * 4 + (rho & 3);
        int sg = l16 ^ (w * 4 + quad);
        gload16(Kb + (long)(k0 + key) * HD + sg * 8, Kd + (i * 256 + w * 64) * 8);
      }
      #pragma unroll
      for (int i = 0; i < 4; i++) {
        int dv = i * 32 + w * 8 + r8;
        int sg = c8 ^ r8;
        gload16(Vb + (long)dv * Ss + k0 + sg * 8, Vd + (i * 256 + w * 64) * 8);
      }
      asm volatile("s_waitcnt vmcnt(8)" ::: "memory");
    } else {
      asm volatile("s_waitcnt vmcnt(0)" ::: "memory");
    }
    asm volatile("s_barrier" ::: "memory");

    if (c * 64 < q0w + 32) {   // skip fully-masked chunks (barriers still uniform)
      // ---- S^T = K . Q^T : 4 rho-tiles x 2 q-tiles ----
      f32x4 sc[2][4] = {};
      #pragma unroll
      for (int T = 0; T < 4; T++)
        #pragma unroll
        for (int kc = 0; kc < 4; kc++) {
          short8 kf = *(const short8*)(Ksb + ((16 * T + l16) * 16 + ((kc * 4 + quad) ^ l16)) * 8);
          #pragma unroll
          for (int qi = 0; qi < 2; qi++)
            sc[qi][T] = __builtin_amdgcn_mfma_f32_16x16x32_bf16(kf, qf[qi][kc], sc[qi][T], 0, 0, 0);
        }

      // ---- causal mask (actual key index accounts for the staging permutation) ----
      if ((c + 1) * 64 - 1 > q0w) {
        #pragma unroll
        for (int qi = 0; qi < 2; qi++) {
          int qq = q0w + qi * 16 + l16;
          #pragma unroll
          for (int T = 0; T < 4; T++)
            #pragma unroll
            for (int r = 0; r < 4; r++) {
              int ka = c * 64 + (T >> 1) * 32 + quad * 8 + (T & 1) * 4 + r;
              if (ka > qq) sc[qi][T][r] = -__builtin_inff();
            }
        }
      }

      // ---- online softmax (row = fixed q = l16; in-lane reduce + xor16/32) ----
      short8 pf[2][2];
      #pragma unroll
      for (int qi = 0; qi < 2; qi++) {
        float v = sc[qi][0][0];
        #pragma unroll
        for (int T = 0; T < 4; T++)
          #pragma unroll
          for (int r = 0; r < 4; r++) v = fmaxf(v, sc[qi][T][r]);
        v = fmaxf(v, __shfl_xor(v, 16));
        v = fmaxf(v, __shfl_xor(v, 32));
        float mn = fmaxf(m_i[qi], v);
        float alpha = __builtin_amdgcn_exp2f((m_i[qi] - mn) * cscale);
        m_i[qi] = mn;
        l_i[qi] *= alpha;
        #pragma unroll
        for (int Dt = 0; Dt < 8; Dt++)
          #pragma unroll
          for (int r = 0; r < 4; r++) accO[qi][Dt][r] *= alpha;

        float p[4][4], rs = 0.f;
        #pragma unroll
        for (int T = 0; T < 4; T++)
          #pragma unroll
          for (int r = 0; r < 4; r++) {
            p[T][r] = __builtin_amdgcn_exp2f((sc[qi][T][r] - mn) * cscale);
            rs += p[T][r];
          }
        rs += __shfl_xor(rs, 16);
        rs += __shfl_xor(rs, 32);
        l_i[qi] += rs;

        #pragma unroll
        for (int c2 = 0; c2 < 2; c2++) {
          short8 f;
          f[0] = (short)f2b(p[2 * c2][0]);     f[1] = (short)f2b(p[2 * c2][1]);
          f[2] = (short)f2b(p[2 * c2][2]);     f[3] = (short)f2b(p[2 * c2][3]);
          f[4] = (short)f2b(p[2 * c2 + 1][0]); f[5] = (short)f2b(p[2 * c2 + 1][1]);
          f[6] = (short)f2b(p[2 * c2 + 1][2]); f[7] = (short)f2b(p[2 * c2 + 1][3]);
          pf[qi][c2] = f;
        }
      }

      // ---- O^T += V^T . P : A = V^T frag (from LDS), B = P frag (in registers) ----
      #pragma unroll
      for (int c2 = 0; c2 < 2; c2++)
        #pragma unroll
        for (int Dt = 0; Dt < 8; Dt++) {
          short8 vf = *(const short8*)(Vsb + ((16 * Dt + l16) * 8 + ((4 * c2 + quad) ^ (l16 & 7))) * 8);
          #pragma unroll
          for (int qi = 0; qi < 2; qi++)
            accO[qi][Dt] = __builtin_amdgcn_mfma_f32_16x16x32_bf16(vf, pf[qi][c2], accO[qi][Dt], 0, 0, 0);
        }
    }

    asm volatile("s_waitcnt lgkmcnt(0)" ::: "memory");
    asm volatile("s_barrier" ::: "memory");
  }

  // ---- epilogue: O^T C-layout -> out[b, s=q, h*HD + d], 8B stores ----
  #pragma unroll
  for (int qi = 0; qi < 2; qi++) {
    float inv = 1.f / l_i[qi];
    long orow = (long)b * Ss + q0w + qi * 16 + l16;
    #pragma unroll
    for (int Dt = 0; Dt < 8; Dt++) {
      ushort4 o;
      o.x = f2b(accO[qi][Dt][0] * inv);
      o.y = f2b(accO[qi][Dt][1] * inv);
      o.z = f2b(accO[qi][Dt][2] * inv);
      o.w = f2b(accO[qi][Dt][3] * inv);
      *(ushort4*)(out + orow * (NH * HD) + h * HD + Dt * 16 + quad * 4) = o;
    }
  }
}

extern "C" void kernel_launch(void* const* d_in, const int* in_sizes, int n_in,
                              void* d_out, int out_size, void* d_ws, size_t ws_size,
                              hipStream_t stream) {
  const float* x   = (const float*)d_in[0];
  const float* cosT = (const float*)d_in[1];
  const float* sinT = (const float*)d_in[2];
  const float* wq  = (const float*)d_in[3];
  const float* wk  = (const float*)d_in[4];
  const float* wv  = (const float*)d_in[5];
  const float* wo  = (const float*)d_in[6];
  float* out = (float*)d_out;

  char* ws = (char*)d_ws;
  unsigned short* xb    = (unsigned short*)(ws + 0);             // 16 MiB
  unsigned short* wqkvt = (unsigned short*)(ws + 16777216);      // 12 MiB
  unsigned short* wot   = (unsigned short*)(ws + 29360128);      // 8 MiB
  unsigned short* qkv   = (unsigned short*)(ws + 37748736);      // 24 MiB
  unsigned short* kt    = (unsigned short*)(ws + 62914560);      // 4 MiB
  unsigned short* vt    = (unsigned short*)(ws + 67108864);      // 4 MiB
  unsigned short* qtp   = xb;    // alias: xb dead after GEMM1
  unsigned short* attno = qkv;   // alias: qkv dead after rope/vtrans

  cvt_bf16<<<Mrows * Hh / 4 / 256, 256, 0, stream>>>(x, xb, Mrows * Hh);

  dim3 tb(32, 8);
  transpose_cvt<<<dim3(Hh / 32, Hh / 32), tb, 0, stream>>>(wq, wqkvt, Hh, NH * HD);
  transpose_cvt<<<dim3(NKV * HD / 32, Hh / 32), tb, 0, stream>>>(wk, wqkvt + (long)NH * HD * Hh, Hh, NKV * HD);
  transpose_cvt<<<dim3(NKV * HD / 32, Hh / 32), tb, 0, stream>>>(wv, wqkvt + (long)(NH * HD + NKV * HD) * Hh, Hh, NKV * HD);
  transpose_cvt<<<dim3(Hh / 32, Hh / 32), tb, 0, stream>>>(wo, wot, Hh, Hh);

  gemm_bt<true><<<dim3(NQKV / 128, Mrows / 128), 256, 0, stream>>>(xb, wqkvt, qkv, Mrows, NQKV, Hh);

  rope_qk<<<Mrows, 256, 0, stream>>>(qkv, cosT, sinT, qtp, kt);
  vtrans<<<dim3(Ss / 32, HD / 32, Bb * NKV), tb, 0, stream>>>(qkv, vt);

  flash_attn<<<(Ss / 128) * NH * Bb, 256, 0, stream>>>(qtp, kt, vt, attno);

  gemm_bt<false><<<dim3(Hh / 128, Mrows / 128), 256, 0, stream>>>(attno, wot, out, Mrows, Hh, Hh);
}